// Round 1
// baseline (1619.774 us; speedup 1.0000x reference)
//
#include <hip/hip_runtime.h>

#define HN 192
#define TT 2048
#define NCLS 12

// Transpose W_cells[l][i][j] -> Wt[l][j][i] so a "column" gather (fixed j,
// lane-varying i) is a coalesced / LDS-conflict-free read.
__global__ void snn_transpose_k(const float* __restrict__ Wc, float* __restrict__ Wt) {
  int idx = blockIdx.x * 256 + threadIdx.x;
  if (idx < 2 * HN * HN) {
    int l = idx / (HN * HN);
    int r = idx - l * HN * HN;
    int i = r / HN;
    int j = r - i * HN;
    Wt[l * HN * HN + j * HN + i] = Wc[idx];
  }
}

// One workgroup per batch element. 192 threads: thread i owns neuron i of
// both layers (v-state in registers). Spikes exchanged as compacted index
// lists in ping-pong LDS buffers; exactly one __syncthreads per timestep.
__global__ __launch_bounds__(HN, 1) void snn_main_k(
    const float* __restrict__ x,        // [B,T,3]
    const float* __restrict__ W_in,     // [H,3]
    const float* __restrict__ b_in,     // [H]
    const float* __restrict__ b_cells,  // [L,H]
    const float* __restrict__ W_head,   // [12,H]
    const float* __restrict__ b_head,   // [12]
    const float* __restrict__ Wt,       // [L,H,H] transposed (j-major)
    float* __restrict__ out)            // [B,12]
{
  extern __shared__ float w0[];  // layer-0 transposed weights, HN*HN floats
  __shared__ __align__(16) unsigned short lists[2][2][3][64]; // [buf][layer][wave][pos]
  __shared__ int cnts[2][2][3];
  __shared__ float feat_lds[HN];

  const int i  = threadIdx.x;   // neuron index 0..191
  const int b  = blockIdx.x;    // batch
  const int wv = i >> 6;        // wave 0..2
  const int ln = i & 63;        // lane

  // Stage layer-0 weights into LDS (float4, coalesced).
  {
    const float4* wsrc = (const float4*)Wt;
    float4* wdst = (float4*)w0;
    for (int idx = i; idx < HN * HN / 4; idx += HN) wdst[idx] = wsrc[idx];
  }
  if (i < 12) ((int*)cnts)[i] = 0;  // t=0 reads zero spike counts (h=0 init)

  const float win0 = W_in[i * 3 + 0];
  const float win1 = W_in[i * 3 + 1];
  const float win2 = W_in[i * 3 + 2];
  const float bi   = b_in[i];
  const float bc0  = b_cells[i];
  const float bc1  = b_cells[HN + i];
  const float* __restrict__ xb  = x + (size_t)b * TT * 3;
  const float* __restrict__ w1g = Wt + HN * HN;   // layer-1 weights (L2)

  float v0 = 0.0f, v1 = 0.0f;
  int cnt = 0;  // spike count of layer-1 neuron i -> exact mean later

  __syncthreads();

  for (int t = 0; t < TT; ++t) {
    const int rb   = t & 1;
    const int wbuf = rb ^ 1;

    // input projection (in_dim = 3), uniform x loads
    const float xv0 = xb[t * 3 + 0];
    const float xv1 = xb[t * 3 + 1];
    const float xv2 = xb[t * 3 + 2];
    const float z = xv0 * win0 + xv1 * win1 + xv2 * win2 + bi;

    float acc0 = z + bc0;
    float acc1 = bc1;

    // ---- layer 0 recurrent gather (weights in LDS) ----
    #pragma unroll
    for (int w = 0; w < 3; ++w) {
      const int n = __builtin_amdgcn_readfirstlane(cnts[rb][0][w]);
      const unsigned short* lst = lists[rb][0][w];
      const unsigned long long* lst4 = (const unsigned long long*)lst;
      const int ngr = n >> 2;
      float pa = 0.0f;
      #pragma unroll 2
      for (int g = 0; g < ngr; ++g) {
        unsigned long long q = lst4[g];
        int j0 = (int)(q & 0xffffull);
        int j1 = (int)((q >> 16) & 0xffffull);
        int j2 = (int)((q >> 32) & 0xffffull);
        int j3 = (int)((q >> 48) & 0xffffull);
        float a0 = w0[j0 * HN + i];
        float a1 = w0[j1 * HN + i];
        float a2 = w0[j2 * HN + i];
        float a3 = w0[j3 * HN + i];
        pa += (a0 + a1) + (a2 + a3);
      }
      for (int p = ngr << 2; p < n; ++p) pa += w0[lst[p] * HN + i];
      acc0 += pa;
    }

    // ---- layer 1 recurrent gather (weights from global/L2) ----
    #pragma unroll
    for (int w = 0; w < 3; ++w) {
      const int n = __builtin_amdgcn_readfirstlane(cnts[rb][1][w]);
      const unsigned short* lst = lists[rb][1][w];
      const unsigned long long* lst4 = (const unsigned long long*)lst;
      const int ngr = n >> 2;
      float pa = 0.0f;
      #pragma unroll 2
      for (int g = 0; g < ngr; ++g) {
        unsigned long long q = lst4[g];
        int j0 = (int)(q & 0xffffull);
        int j1 = (int)((q >> 16) & 0xffffull);
        int j2 = (int)((q >> 32) & 0xffffull);
        int j3 = (int)((q >> 48) & 0xffffull);
        float a0 = w1g[j0 * HN + i];
        float a1 = w1g[j1 * HN + i];
        float a2 = w1g[j2 * HN + i];
        float a3 = w1g[j3 * HN + i];
        pa += (a0 + a1) + (a2 + a3);
      }
      for (int p = ngr << 2; p < n; ++p) pa += w1g[lst[p] * HN + i];
      acc1 += pa;
    }

    // ---- LIF layer 0 (exact fp32, matches reference ops) ----
    v0 = v0 + (acc0 - v0) * 0.5f;
    const bool sp0 = (v0 >= 1.0f);
    const float s0 = sp0 ? 1.0f : 0.0f;
    if (sp0) v0 = 0.0f;
    unsigned long long mb = __ballot(sp0 ? 1 : 0);
    if (sp0) {
      int pos = (int)__popcll(mb & ((1ull << ln) - 1ull));
      lists[wbuf][0][wv][pos] = (unsigned short)i;
    }
    if (ln == 0) cnts[wbuf][0][wv] = (int)__popcll(mb);

    // ---- LIF layer 1 ----
    acc1 += s0;  // z-chain: layer-1 pre-activation includes own s0
    v1 = v1 + (acc1 - v1) * 0.5f;
    const bool sp1 = (v1 >= 1.0f);
    if (sp1) { v1 = 0.0f; cnt++; }
    mb = __ballot(sp1 ? 1 : 0);
    if (sp1) {
      int pos = (int)__popcll(mb & ((1ull << ln) - 1ull));
      lists[wbuf][1][wv][pos] = (unsigned short)i;
    }
    if (ln == 0) cnts[wbuf][1][wv] = (int)__popcll(mb);

    __syncthreads();  // the single per-step barrier (ping-pong buffers)
  }

  // ---- epilogue: exact mean (count/2048) + head GEMV ----
  feat_lds[i] = (float)cnt * (1.0f / 2048.0f);
  __syncthreads();
  if (i < NCLS) {
    float acc = b_head[i];
    #pragma unroll 8
    for (int q = 0; q < HN; ++q) acc += feat_lds[q] * W_head[i * HN + q];
    out[b * NCLS + i] = acc;
  }
}

extern "C" void kernel_launch(void* const* d_in, const int* in_sizes, int n_in,
                              void* d_out, int out_size, void* d_ws, size_t ws_size,
                              hipStream_t stream) {
  const float* x       = (const float*)d_in[0];
  const float* W_in    = (const float*)d_in[1];
  const float* b_in    = (const float*)d_in[2];
  const float* W_cells = (const float*)d_in[3];
  const float* b_cells = (const float*)d_in[4];
  const float* W_head  = (const float*)d_in[5];
  const float* b_head  = (const float*)d_in[6];
  float* out = (float*)d_out;
  float* Wt  = (float*)d_ws;  // 2*192*192 fp32 = 294912 B of scratch

  snn_transpose_k<<<(2 * HN * HN + 255) / 256, 256, 0, stream>>>(W_cells, Wt);
  snn_main_k<<<128, HN, HN * HN * sizeof(float), stream>>>(
      x, W_in, b_in, b_cells, W_head, b_head, Wt, out);
}